// Round 1
// baseline (606.678 us; speedup 1.0000x reference)
//
#include <hip/hip_runtime.h>

#define N_NODES 50000
#define N_EDGES 600000
#define D 128
#define TILE_N 32
#define SCAN_T 1024
#define PER_T ((N_NODES + SCAN_T - 1) / SCAN_T)   // 49

// ===========================================================================
// Path: 1-pass rank-recording histogram -> single-block scan ->
//       atomic-free CSR fill -> 4-deep-prefetch gather-aggregate ->
//       LDS GEMM epilogue.
//   agg[n] = h[n] .* sum_{e: dst[e]=n} e_h[e]   (A, staged in ws)
//   out    = (A @ W^T + b) * norm
// ===========================================================================

// hist + per-edge rank: rank[e] = position of e within its node's bucket.
// Single atomic pass over edges (replaces the old hist + atomic-cursor fill).
__global__ __launch_bounds__(256) void hist_kernel(
    const int* __restrict__ dst, int* __restrict__ cnt, int* __restrict__ rank)
{
    int e = blockIdx.x * 256 + threadIdx.x;
    if (e < N_EDGES) rank[e] = atomicAdd(&cnt[dst[e]], 1);
}

// Single-block scan of 50K counts (200 KB — launch overhead of the old
// 3-kernel hierarchical scan dwarfed the work). 1024 threads x 49 elems.
__global__ __launch_bounds__(SCAN_T) void scan_kernel(
    const int* __restrict__ cnt, int* __restrict__ offsets)
{
    __shared__ int part[SCAN_T];
    const int t = threadIdx.x;
    const int base = t * PER_T;
    int s = 0;
    for (int k = 0; k < PER_T; ++k) {
        int i = base + k;
        if (i < N_NODES) s += cnt[i];
    }
    part[t] = s;
    __syncthreads();
    for (int st = 1; st < SCAN_T; st <<= 1) {
        int u = (t >= st) ? part[t - st] : 0;
        __syncthreads();
        part[t] += u;
        __syncthreads();
    }
    int run = part[t] - s;      // exclusive prefix of this thread's chunk
    for (int k = 0; k < PER_T; ++k) {
        int i = base + k;
        if (i < N_NODES) { offsets[i] = run; run += cnt[i]; }
    }
    if (t == SCAN_T - 1) offsets[N_NODES] = run;   // == N_EDGES
}

// Atomic-free fill: offsets is 200 KB -> L2-resident random gather.
__global__ __launch_bounds__(256) void fill_kernel(
    const int* __restrict__ dst, const int* __restrict__ rank,
    const int* __restrict__ offsets, int* __restrict__ edge_ids)
{
    int e = blockIdx.x * 256 + threadIdx.x;
    if (e < N_EDGES) edge_ids[offsets[dst[e]] + rank[e]] = e;
}

// ---------------------------------------------------------------------------
// Aggregate: A[n] = h[n] .* sum(e_h rows). 32 lanes/node, one float4/lane.
// Unroll-by-4: batch 4 edge ids, issue 4 independent 512B row loads before
// any waitcnt -> 4 outstanding HBM loads per node stream (was 1). Separate
// accumulators break the FMA dependence chain.
// ---------------------------------------------------------------------------
__global__ __launch_bounds__(256) void agg_kernel(
    const float* __restrict__ h, const float* __restrict__ e_h,
    const int* __restrict__ offsets, const int* __restrict__ edge_ids,
    float* __restrict__ A)
{
    int gid  = blockIdx.x * 256 + threadIdx.x;
    int node = gid >> 5;
    int lane = gid & 31;
    if (node >= N_NODES) return;

    const int beg = offsets[node];
    const int end = offsets[node + 1];
    const float* eb = e_h + (lane << 2);

    float4 a0 = make_float4(0.f, 0.f, 0.f, 0.f);
    float4 a1 = make_float4(0.f, 0.f, 0.f, 0.f);
    float4 a2 = make_float4(0.f, 0.f, 0.f, 0.f);
    float4 a3 = make_float4(0.f, 0.f, 0.f, 0.f);

    int i = beg;
    for (; i + 4 <= end; i += 4) {
        int i0 = edge_ids[i + 0];
        int i1 = edge_ids[i + 1];
        int i2 = edge_ids[i + 2];
        int i3 = edge_ids[i + 3];
        float4 v0 = *(const float4*)(eb + ((size_t)i0 << 7));
        float4 v1 = *(const float4*)(eb + ((size_t)i1 << 7));
        float4 v2 = *(const float4*)(eb + ((size_t)i2 << 7));
        float4 v3 = *(const float4*)(eb + ((size_t)i3 << 7));
        a0.x += v0.x; a0.y += v0.y; a0.z += v0.z; a0.w += v0.w;
        a1.x += v1.x; a1.y += v1.y; a1.z += v1.z; a1.w += v1.w;
        a2.x += v2.x; a2.y += v2.y; a2.z += v2.z; a2.w += v2.w;
        a3.x += v3.x; a3.y += v3.y; a3.z += v3.z; a3.w += v3.w;
    }
    for (; i < end; ++i) {
        int id = edge_ids[i];
        float4 v = *(const float4*)(eb + ((size_t)id << 7));
        a0.x += v.x; a0.y += v.y; a0.z += v.z; a0.w += v.w;
    }
    a0.x += a1.x + a2.x + a3.x;
    a0.y += a1.y + a2.y + a3.y;
    a0.z += a1.z + a2.z + a3.z;
    a0.w += a1.w + a2.w + a3.w;

    float4 hv = *(const float4*)(h + ((size_t)node << 7) + (lane << 2));
    a0.x *= hv.x; a0.y *= hv.y; a0.z *= hv.z; a0.w *= hv.w;
    *(float4*)(A + ((size_t)node << 7) + (lane << 2)) = a0;
}

// ---------------------------------------------------------------------------
// GEMM: out = (A @ W^T + b) * norm.  32 nodes x 128 cols / block.
// W granule-swizzled in LDS (64KB) + A tile (16KB) -> 2 blocks/CU.
// Per thread 4 nodes x 4 cols. (Unchanged — verified structure.)
// ---------------------------------------------------------------------------
__global__ __launch_bounds__(256, 2) void gemm_from_A(
    const float* __restrict__ A, const float* __restrict__ norm,
    const float* __restrict__ W, const float* __restrict__ b,
    float* __restrict__ out)
{
    __shared__ float Wl[D * D];
    __shared__ float Al[TILE_N * D];
    const int tid = threadIdx.x;
    const int n0  = blockIdx.x * TILE_N;

    for (int it = 0; it < 16; ++it) {
        int group = it * 256 + tid;
        int c  = group >> 5;
        int kg = group & 31;
        float4 wv = *(const float4*)(W + (size_t)c * D + (kg << 2));
        int g = (kg + c) & 31;
        *(float4*)(Wl + c * D + (g << 2)) = wv;
    }
    for (int it = 0; it < 4; ++it) {
        int group = it * 256 + tid;
        int nl = group >> 5;
        int f  = (group & 31) << 2;
        int n  = n0 + nl;
        float4 a = make_float4(0.f, 0.f, 0.f, 0.f);
        if (n < N_NODES) a = *(const float4*)(A + (size_t)n * D + f);
        *(float4*)(Al + nl * D + f) = a;
    }
    __syncthreads();

    const int cg = tid & 31;
    const int ng = tid >> 5;
    float facc[4][4];
#pragma unroll
    for (int i = 0; i < 4; ++i)
#pragma unroll
        for (int j = 0; j < 4; ++j) facc[i][j] = 0.f;

#pragma unroll 4
    for (int kc = 0; kc < 32; ++kc) {
        float4 a[4];
#pragma unroll
        for (int i = 0; i < 4; ++i)
            a[i] = *(const float4*)(Al + (ng * 4 + i) * D + (kc << 2));
        float4 w[4];
#pragma unroll
        for (int j = 0; j < 4; ++j) {
            int c = cg + 32 * j;
            int g = (kc + c) & 31;
            w[j] = *(const float4*)(Wl + c * D + (g << 2));
        }
#pragma unroll
        for (int i = 0; i < 4; ++i)
#pragma unroll
            for (int j = 0; j < 4; ++j)
                facc[i][j] += a[i].x * w[j].x + a[i].y * w[j].y +
                              a[i].z * w[j].z + a[i].w * w[j].w;
    }
    float bias[4];
#pragma unroll
    for (int j = 0; j < 4; ++j) bias[j] = b[cg + 32 * j];
#pragma unroll
    for (int i = 0; i < 4; ++i) {
        int n = n0 + ng * 4 + i;
        if (n >= N_NODES) break;
        float nv = norm[n];
#pragma unroll
        for (int j = 0; j < 4; ++j)
            out[(size_t)n * D + cg + 32 * j] = (facc[i][j] + bias[j]) * nv;
    }
}

// ===========================================================================
// Fallback (tiny ws): float-atomic scatter + fused gemm
// ===========================================================================
__global__ __launch_bounds__(256) void scatter_kernel(
    const float* __restrict__ e_h, const int* __restrict__ dst,
    float* __restrict__ S)
{
    long long idx = (long long)blockIdx.x * 256 + threadIdx.x;
    int edge = (int)(idx >> 5);
    if (edge >= N_EDGES) return;
    int f = ((int)idx & 31) << 2;
    const float4 v = *(const float4*)(e_h + (size_t)edge * D + f);
    float* p = S + (size_t)dst[edge] * D + f;
    atomicAdd(p + 0, v.x);
    atomicAdd(p + 1, v.y);
    atomicAdd(p + 2, v.z);
    atomicAdd(p + 3, v.w);
}

__global__ __launch_bounds__(256, 2) void gemm_kernel(
    const float* __restrict__ h, const float* __restrict__ S,
    const float* __restrict__ norm, const float* __restrict__ W,
    const float* __restrict__ b, float* __restrict__ out)
{
    __shared__ float Wl[D * D];
    __shared__ float Al[TILE_N * D];
    const int tid = threadIdx.x;
    const int n0  = blockIdx.x * TILE_N;

    for (int it = 0; it < 16; ++it) {
        int group = it * 256 + tid;
        int c  = group >> 5;
        int kg = group & 31;
        float4 wv = *(const float4*)(W + (size_t)c * D + (kg << 2));
        int g = (kg + c) & 31;
        *(float4*)(Wl + c * D + (g << 2)) = wv;
    }
    for (int it = 0; it < 4; ++it) {
        int group = it * 256 + tid;
        int nl = group >> 5;
        int f  = (group & 31) << 2;
        int n  = n0 + nl;
        float4 a = make_float4(0.f, 0.f, 0.f, 0.f);
        if (n < N_NODES) {
            float4 hv = *(const float4*)(h + (size_t)n * D + f);
            float4 sv = *(const float4*)(S + (size_t)n * D + f);
            a = make_float4(hv.x * sv.x, hv.y * sv.y, hv.z * sv.z, hv.w * sv.w);
        }
        *(float4*)(Al + nl * D + f) = a;
    }
    __syncthreads();

    const int cg = tid & 31;
    const int ng = tid >> 5;
    float facc[4][4];
#pragma unroll
    for (int i = 0; i < 4; ++i)
#pragma unroll
        for (int j = 0; j < 4; ++j) facc[i][j] = 0.f;

#pragma unroll 4
    for (int kc = 0; kc < 32; ++kc) {
        float4 a[4];
#pragma unroll
        for (int i = 0; i < 4; ++i)
            a[i] = *(const float4*)(Al + (ng * 4 + i) * D + (kc << 2));
        float4 w[4];
#pragma unroll
        for (int j = 0; j < 4; ++j) {
            int c = cg + 32 * j;
            int g = (kc + c) & 31;
            w[j] = *(const float4*)(Wl + c * D + (g << 2));
        }
#pragma unroll
        for (int i = 0; i < 4; ++i)
#pragma unroll
            for (int j = 0; j < 4; ++j)
                facc[i][j] += a[i].x * w[j].x + a[i].y * w[j].y +
                              a[i].z * w[j].z + a[i].w * w[j].w;
    }
    float bias[4];
#pragma unroll
    for (int j = 0; j < 4; ++j) bias[j] = b[cg + 32 * j];
#pragma unroll
    for (int i = 0; i < 4; ++i) {
        int n = n0 + ng * 4 + i;
        if (n >= N_NODES) break;
        float nv = norm[n];
#pragma unroll
        for (int j = 0; j < 4; ++j)
            out[(size_t)n * D + cg + 32 * j] = (facc[i][j] + bias[j]) * nv;
    }
}

// ===========================================================================
extern "C" void kernel_launch(void* const* d_in, const int* in_sizes, int n_in,
                              void* d_out, int out_size, void* d_ws, size_t ws_size,
                              hipStream_t stream) {
    const float* h    = (const float*)d_in[0];
    const float* e_h  = (const float*)d_in[1];
    const float* norm = (const float*)d_in[2];
    const int*   dst  = (const int*)d_in[3];
    const float* W    = (const float*)d_in[4];
    const float* b    = (const float*)d_in[5];
    float* out = (float*)d_out;

    // ws layout: A[N*D] (16B-aligned first) | cnt[N] | offsets[N+1] | rank[E] | edge_ids[E]
    const size_t ints_needed = (size_t)N_NODES + (N_NODES + 1) + 2 * (size_t)N_EDGES;
    const size_t full_bytes  = (size_t)N_NODES * D * sizeof(float) + ints_needed * sizeof(int);

    if (ws_size >= full_bytes) {
        float* A      = (float*)d_ws;
        int* cnt      = (int*)(A + (size_t)N_NODES * D);
        int* offsets  = cnt + N_NODES;
        int* rank     = offsets + N_NODES + 1;
        int* edge_ids = rank + N_EDGES;

        hipMemsetAsync(cnt, 0, (size_t)N_NODES * sizeof(int), stream);

        int eblocks = (N_EDGES + 255) / 256;
        hist_kernel<<<eblocks, 256, 0, stream>>>(dst, cnt, rank);
        scan_kernel<<<1, SCAN_T, 0, stream>>>(cnt, offsets);
        fill_kernel<<<eblocks, 256, 0, stream>>>(dst, rank, offsets, edge_ids);

        int ablocks = ((N_NODES * 32) + 255) / 256;   // 6250
        agg_kernel<<<ablocks, 256, 0, stream>>>(h, e_h, offsets, edge_ids, A);

        int gblocks = (N_NODES + TILE_N - 1) / TILE_N;  // 1563
        gemm_from_A<<<gblocks, 256, 0, stream>>>(A, norm, W, b, out);
    } else {
        const size_t s_bytes = (size_t)N_NODES * D * sizeof(float);
        float* S = (ws_size >= s_bytes) ? (float*)d_ws : out;
        hipMemsetAsync(S, 0, s_bytes, stream);
        int scatter_blocks = (N_EDGES * 32 + 255) / 256;
        scatter_kernel<<<scatter_blocks, 256, 0, stream>>>(e_h, dst, S);
        int gemm_blocks = (N_NODES + TILE_N - 1) / TILE_N;
        gemm_kernel<<<gemm_blocks, 256, 0, stream>>>(h, S, norm, W, b, out);
    }
}

// Round 2
// 549.485 us; speedup vs baseline: 1.1041x; 1.1041x over previous
//
#include <hip/hip_runtime.h>

#define N_NODES 50000
#define N_EDGES 600000
#define D 128
#define TILE_N 32
#define SCAN_B 1024
#define N_SCAN_BLOCKS ((N_NODES + SCAN_B - 1) / SCAN_B)   // 49

// ===========================================================================
// Path: CSR build (int atomics only, proven-baseline structure) ->
//       windowed-8 gather-aggregate -> LDS GEMM epilogue.
//   agg[n] = h[n] .* sum_{e: dst[e]=n} e_h[e]   (A, staged in ws)
//   out    = (A @ W^T + b) * norm
// ===========================================================================

__global__ __launch_bounds__(256) void hist_kernel(
    const int* __restrict__ dst, int* __restrict__ cnt)
{
    int e = blockIdx.x * 256 + threadIdx.x;
    if (e < N_EDGES) atomicAdd(&cnt[dst[e]], 1);
}

// --- hierarchical scan: per-block sums -> scan partials -> emit offsets ---
__global__ __launch_bounds__(SCAN_B) void scan_sum_kernel(
    const int* __restrict__ cnt, int* __restrict__ partial)
{
    int t = threadIdx.x;
    int i = blockIdx.x * SCAN_B + t;
    int v = (i < N_NODES) ? cnt[i] : 0;
#pragma unroll
    for (int s = 32; s > 0; s >>= 1) v += __shfl_down(v, s, 64);
    __shared__ int wsum[SCAN_B / 64];
    if ((t & 63) == 0) wsum[t >> 6] = v;
    __syncthreads();
    if (t < SCAN_B / 64) {
        int x = wsum[t];
#pragma unroll
        for (int s = SCAN_B / 128; s > 0; s >>= 1) x += __shfl_down(x, s, SCAN_B / 64);
        if (t == 0) partial[blockIdx.x] = x;
    }
}

__global__ __launch_bounds__(64) void scan_partial_kernel(int* __restrict__ partial)
{
    int t = threadIdx.x;
    int v = (t < N_SCAN_BLOCKS) ? partial[t] : 0;
    int own = v;
#pragma unroll
    for (int s = 1; s < 64; s <<= 1) {
        int u = __shfl_up(v, s, 64);
        if (t >= s) v += u;
    }
    if (t < N_SCAN_BLOCKS) partial[t] = v - own;   // exclusive prefix
}

__global__ __launch_bounds__(SCAN_B) void scan_emit_kernel(
    const int* __restrict__ cnt, const int* __restrict__ partial,
    int* __restrict__ offsets, int* __restrict__ cursor)
{
    int t = threadIdx.x;
    int i = blockIdx.x * SCAN_B + t;
    int v = (i < N_NODES) ? cnt[i] : 0;
    __shared__ int sd[SCAN_B];
    sd[t] = v;
    __syncthreads();
    for (int s = 1; s < SCAN_B; s <<= 1) {
        int u = (t >= s) ? sd[t - s] : 0;
        __syncthreads();
        sd[t] += u;
        __syncthreads();
    }
    int excl = sd[t] - v + partial[blockIdx.x];
    if (i < N_NODES) { offsets[i] = excl; cursor[i] = excl; }
    if (i == N_NODES - 1) offsets[N_NODES] = excl + v;   // == N_EDGES
}

__global__ __launch_bounds__(256) void fill_kernel(
    const int* __restrict__ dst, int* __restrict__ cursor,
    int* __restrict__ edge_ids)
{
    int e = blockIdx.x * 256 + threadIdx.x;
    if (e < N_EDGES) {
        int pos = atomicAdd(&cursor[dst[e]], 1);
        edge_ids[pos] = e;
    }
}

// ---------------------------------------------------------------------------
// Aggregate: A[n] = h[n] .* sum(e_h rows). 32 lanes/node, one float4/lane.
// Windowed-8 gather: load up to 8 edge ids (one vmcnt wait), then issue up
// to 8 independent 512B row loads before any accumulate -> 8 outstanding
// HBM loads per node stream (16/wave). All window slots are named scalars
// (static indexing); guards fold at compile time. 4 rotating accumulators
// break the FMA dependence chain.
// ---------------------------------------------------------------------------
__global__ __launch_bounds__(256) void agg_kernel(
    const float* __restrict__ h, const float* __restrict__ e_h,
    const int* __restrict__ offsets, const int* __restrict__ edge_ids,
    float* __restrict__ A)
{
    int gid  = blockIdx.x * 256 + threadIdx.x;
    int node = gid >> 5;
    int lane = gid & 31;
    if (node >= N_NODES) return;

    const int beg = offsets[node];
    const int end = offsets[node + 1];
    const float* eb = e_h + (lane << 2);

    float4 a0 = make_float4(0.f, 0.f, 0.f, 0.f);
    float4 a1 = a0, a2 = a0, a3 = a0;

    for (int i = beg; i < end; i += 8) {
        const int m = end - i;          // >= 1
        int i0, i1, i2, i3, i4, i5, i6, i7;
        i0 = edge_ids[i];
        if (m > 1) i1 = edge_ids[i + 1];
        if (m > 2) i2 = edge_ids[i + 2];
        if (m > 3) i3 = edge_ids[i + 3];
        if (m > 4) i4 = edge_ids[i + 4];
        if (m > 5) i5 = edge_ids[i + 5];
        if (m > 6) i6 = edge_ids[i + 6];
        if (m > 7) i7 = edge_ids[i + 7];

        float4 v0, v1, v2, v3, v4, v5, v6, v7;
        v0 = *(const float4*)(eb + ((size_t)i0 << 7));
        if (m > 1) v1 = *(const float4*)(eb + ((size_t)i1 << 7));
        if (m > 2) v2 = *(const float4*)(eb + ((size_t)i2 << 7));
        if (m > 3) v3 = *(const float4*)(eb + ((size_t)i3 << 7));
        if (m > 4) v4 = *(const float4*)(eb + ((size_t)i4 << 7));
        if (m > 5) v5 = *(const float4*)(eb + ((size_t)i5 << 7));
        if (m > 6) v6 = *(const float4*)(eb + ((size_t)i6 << 7));
        if (m > 7) v7 = *(const float4*)(eb + ((size_t)i7 << 7));

        a0.x += v0.x; a0.y += v0.y; a0.z += v0.z; a0.w += v0.w;
        if (m > 1) { a1.x += v1.x; a1.y += v1.y; a1.z += v1.z; a1.w += v1.w; }
        if (m > 2) { a2.x += v2.x; a2.y += v2.y; a2.z += v2.z; a2.w += v2.w; }
        if (m > 3) { a3.x += v3.x; a3.y += v3.y; a3.z += v3.z; a3.w += v3.w; }
        if (m > 4) { a0.x += v4.x; a0.y += v4.y; a0.z += v4.z; a0.w += v4.w; }
        if (m > 5) { a1.x += v5.x; a1.y += v5.y; a1.z += v5.z; a1.w += v5.w; }
        if (m > 6) { a2.x += v6.x; a2.y += v6.y; a2.z += v6.z; a2.w += v6.w; }
        if (m > 7) { a3.x += v7.x; a3.y += v7.y; a3.z += v7.z; a3.w += v7.w; }
    }

    a0.x += a1.x + a2.x + a3.x;
    a0.y += a1.y + a2.y + a3.y;
    a0.z += a1.z + a2.z + a3.z;
    a0.w += a1.w + a2.w + a3.w;

    float4 hv = *(const float4*)(h + ((size_t)node << 7) + (lane << 2));
    a0.x *= hv.x; a0.y *= hv.y; a0.z *= hv.z; a0.w *= hv.w;
    *(float4*)(A + ((size_t)node << 7) + (lane << 2)) = a0;
}

// ---------------------------------------------------------------------------
// GEMM: out = (A @ W^T + b) * norm.  32 nodes x 128 cols / block.
// W granule-swizzled in LDS (64KB) + A tile (16KB) -> 2 blocks/CU.
// Per thread 4 nodes x 4 cols. (Unchanged — verified structure.)
// ---------------------------------------------------------------------------
__global__ __launch_bounds__(256, 2) void gemm_from_A(
    const float* __restrict__ A, const float* __restrict__ norm,
    const float* __restrict__ W, const float* __restrict__ b,
    float* __restrict__ out)
{
    __shared__ float Wl[D * D];
    __shared__ float Al[TILE_N * D];
    const int tid = threadIdx.x;
    const int n0  = blockIdx.x * TILE_N;

    for (int it = 0; it < 16; ++it) {
        int group = it * 256 + tid;
        int c  = group >> 5;
        int kg = group & 31;
        float4 wv = *(const float4*)(W + (size_t)c * D + (kg << 2));
        int g = (kg + c) & 31;
        *(float4*)(Wl + c * D + (g << 2)) = wv;
    }
    for (int it = 0; it < 4; ++it) {
        int group = it * 256 + tid;
        int nl = group >> 5;
        int f  = (group & 31) << 2;
        int n  = n0 + nl;
        float4 a = make_float4(0.f, 0.f, 0.f, 0.f);
        if (n < N_NODES) a = *(const float4*)(A + (size_t)n * D + f);
        *(float4*)(Al + nl * D + f) = a;
    }
    __syncthreads();

    const int cg = tid & 31;
    const int ng = tid >> 5;
    float facc[4][4];
#pragma unroll
    for (int i = 0; i < 4; ++i)
#pragma unroll
        for (int j = 0; j < 4; ++j) facc[i][j] = 0.f;

#pragma unroll 4
    for (int kc = 0; kc < 32; ++kc) {
        float4 a[4];
#pragma unroll
        for (int i = 0; i < 4; ++i)
            a[i] = *(const float4*)(Al + (ng * 4 + i) * D + (kc << 2));
        float4 w[4];
#pragma unroll
        for (int j = 0; j < 4; ++j) {
            int c = cg + 32 * j;
            int g = (kc + c) & 31;
            w[j] = *(const float4*)(Wl + c * D + (g << 2));
        }
#pragma unroll
        for (int i = 0; i < 4; ++i)
#pragma unroll
            for (int j = 0; j < 4; ++j)
                facc[i][j] += a[i].x * w[j].x + a[i].y * w[j].y +
                              a[i].z * w[j].z + a[i].w * w[j].w;
    }
    float bias[4];
#pragma unroll
    for (int j = 0; j < 4; ++j) bias[j] = b[cg + 32 * j];
#pragma unroll
    for (int i = 0; i < 4; ++i) {
        int n = n0 + ng * 4 + i;
        if (n >= N_NODES) break;
        float nv = norm[n];
#pragma unroll
        for (int j = 0; j < 4; ++j)
            out[(size_t)n * D + cg + 32 * j] = (facc[i][j] + bias[j]) * nv;
    }
}

// ===========================================================================
// Fallback (tiny ws): float-atomic scatter + fused gemm
// ===========================================================================
__global__ __launch_bounds__(256) void scatter_kernel(
    const float* __restrict__ e_h, const int* __restrict__ dst,
    float* __restrict__ S)
{
    long long idx = (long long)blockIdx.x * 256 + threadIdx.x;
    int edge = (int)(idx >> 5);
    if (edge >= N_EDGES) return;
    int f = ((int)idx & 31) << 2;
    const float4 v = *(const float4*)(e_h + (size_t)edge * D + f);
    float* p = S + (size_t)dst[edge] * D + f;
    atomicAdd(p + 0, v.x);
    atomicAdd(p + 1, v.y);
    atomicAdd(p + 2, v.z);
    atomicAdd(p + 3, v.w);
}

__global__ __launch_bounds__(256, 2) void gemm_kernel(
    const float* __restrict__ h, const float* __restrict__ S,
    const float* __restrict__ norm, const float* __restrict__ W,
    const float* __restrict__ b, float* __restrict__ out)
{
    __shared__ float Wl[D * D];
    __shared__ float Al[TILE_N * D];
    const int tid = threadIdx.x;
    const int n0  = blockIdx.x * TILE_N;

    for (int it = 0; it < 16; ++it) {
        int group = it * 256 + tid;
        int c  = group >> 5;
        int kg = group & 31;
        float4 wv = *(const float4*)(W + (size_t)c * D + (kg << 2));
        int g = (kg + c) & 31;
        *(float4*)(Wl + c * D + (g << 2)) = wv;
    }
    for (int it = 0; it < 4; ++it) {
        int group = it * 256 + tid;
        int nl = group >> 5;
        int f  = (group & 31) << 2;
        int n  = n0 + nl;
        float4 a = make_float4(0.f, 0.f, 0.f, 0.f);
        if (n < N_NODES) {
            float4 hv = *(const float4*)(h + (size_t)n * D + f);
            float4 sv = *(const float4*)(S + (size_t)n * D + f);
            a = make_float4(hv.x * sv.x, hv.y * sv.y, hv.z * sv.z, hv.w * sv.w);
        }
        *(float4*)(Al + nl * D + f) = a;
    }
    __syncthreads();

    const int cg = tid & 31;
    const int ng = tid >> 5;
    float facc[4][4];
#pragma unroll
    for (int i = 0; i < 4; ++i)
#pragma unroll
        for (int j = 0; j < 4; ++j) facc[i][j] = 0.f;

#pragma unroll 4
    for (int kc = 0; kc < 32; ++kc) {
        float4 a[4];
#pragma unroll
        for (int i = 0; i < 4; ++i)
            a[i] = *(const float4*)(Al + (ng * 4 + i) * D + (kc << 2));
        float4 w[4];
#pragma unroll
        for (int j = 0; j < 4; ++j) {
            int c = cg + 32 * j;
            int g = (kc + c) & 31;
            w[j] = *(const float4*)(Wl + c * D + (g << 2));
        }
#pragma unroll
        for (int i = 0; i < 4; ++i)
#pragma unroll
            for (int j = 0; j < 4; ++j)
                facc[i][j] += a[i].x * w[j].x + a[i].y * w[j].y +
                              a[i].z * w[j].z + a[i].w * w[j].w;
    }
    float bias[4];
#pragma unroll
    for (int j = 0; j < 4; ++j) bias[j] = b[cg + 32 * j];
#pragma unroll
    for (int i = 0; i < 4; ++i) {
        int n = n0 + ng * 4 + i;
        if (n >= N_NODES) break;
        float nv = norm[n];
#pragma unroll
        for (int j = 0; j < 4; ++j)
            out[(size_t)n * D + cg + 32 * j] = (facc[i][j] + bias[j]) * nv;
    }
}

// ===========================================================================
extern "C" void kernel_launch(void* const* d_in, const int* in_sizes, int n_in,
                              void* d_out, int out_size, void* d_ws, size_t ws_size,
                              hipStream_t stream) {
    const float* h    = (const float*)d_in[0];
    const float* e_h  = (const float*)d_in[1];
    const float* norm = (const float*)d_in[2];
    const int*   dst  = (const int*)d_in[3];
    const float* W    = (const float*)d_in[4];
    const float* b    = (const float*)d_in[5];
    float* out = (float*)d_out;

    // ws layout: A[N*D] (16B-aligned first) | cursor[N] | offsets[N+1] |
    //            edge_ids[E] | partial[64]
    const size_t ints_needed = (size_t)N_NODES + (N_NODES + 1) + N_EDGES + 64;
    const size_t full_bytes  = (size_t)N_NODES * D * sizeof(float) + ints_needed * sizeof(int);

    if (ws_size >= full_bytes) {
        float* A      = (float*)d_ws;
        int* cursor   = (int*)(A + (size_t)N_NODES * D);
        int* offsets  = cursor + N_NODES;
        int* edge_ids = offsets + N_NODES + 1;
        int* partial  = edge_ids + N_EDGES;

        hipMemsetAsync(cursor, 0, (size_t)N_NODES * sizeof(int), stream);

        int eblocks = (N_EDGES + 255) / 256;
        hist_kernel<<<eblocks, 256, 0, stream>>>(dst, cursor);
        scan_sum_kernel<<<N_SCAN_BLOCKS, SCAN_B, 0, stream>>>(cursor, partial);
        scan_partial_kernel<<<1, 64, 0, stream>>>(partial);
        scan_emit_kernel<<<N_SCAN_BLOCKS, SCAN_B, 0, stream>>>(cursor, partial,
                                                               offsets, cursor);
        fill_kernel<<<eblocks, 256, 0, stream>>>(dst, cursor, edge_ids);

        int ablocks = ((N_NODES * 32) + 255) / 256;   // 6250
        agg_kernel<<<ablocks, 256, 0, stream>>>(h, e_h, offsets, edge_ids, A);

        int gblocks = (N_NODES + TILE_N - 1) / TILE_N;  // 1563
        gemm_from_A<<<gblocks, 256, 0, stream>>>(A, norm, W, b, out);
    } else {
        const size_t s_bytes = (size_t)N_NODES * D * sizeof(float);
        float* S = (ws_size >= s_bytes) ? (float*)d_ws : out;
        hipMemsetAsync(S, 0, s_bytes, stream);
        int scatter_blocks = (N_EDGES * 32 + 255) / 256;
        scatter_kernel<<<scatter_blocks, 256, 0, stream>>>(e_h, dst, S);
        int gemm_blocks = (N_NODES + TILE_N - 1) / TILE_N;
        gemm_kernel<<<gemm_blocks, 256, 0, stream>>>(h, S, norm, W, b, out);
    }
}

// Round 3
// 525.611 us; speedup vs baseline: 1.1542x; 1.0454x over previous
//
#include <hip/hip_runtime.h>

#define N_NODES 50000
#define N_EDGES 600000
#define D 128
#define TILE_N 32
#define SCAN_B 1024
#define N_SCAN_BLOCKS ((N_NODES + SCAN_B - 1) / SCAN_B)   // 49

// ===========================================================================
// Path (5 dispatches):
//   memset(cnt) -> hist_rank (1 atomic pass, records per-edge rank)
//   -> scan_offsets (one kernel, 49 blocks; each block sums its preceding
//      counts itself — coalesced, multi-CU; avoids R1's 1-block-scan trap)
//   -> fill_free (atomic-free CSR fill via offsets[dst]+rank)
//   -> fused_agg_gemm (gather-aggregate tile into LDS, then GEMM epilogue;
//      A never touches HBM).
//   out = ((h .* sum_{e->n} e_h[e]) @ W^T + b) * norm
// ===========================================================================

__global__ __launch_bounds__(256) void hist_rank_kernel(
    const int* __restrict__ dst, int* __restrict__ cnt, int* __restrict__ rank)
{
    int e = blockIdx.x * 256 + threadIdx.x;
    if (e < N_EDGES) rank[e] = atomicAdd(&cnt[dst[e]], 1);
}

// One-kernel scan: block b computes base = sum(cnt[0 .. b*1024)) itself
// (coalesced grid-stride reads, L2-resident), then a local Hillis-Steele
// scan of its own 1024 counts. 49 blocks -> spreads across CUs.
__global__ __launch_bounds__(SCAN_B) void scan_offsets_kernel(
    const int* __restrict__ cnt, int* __restrict__ offsets)
{
    const int t = threadIdx.x;
    const int b = blockIdx.x;
    const int i = b * SCAN_B + t;
    int v = (i < N_NODES) ? cnt[i] : 0;

    // --- base = sum of all counts before this block ---
    int part = 0;
    for (int j = t; j < b * SCAN_B; j += SCAN_B) part += cnt[j];
#pragma unroll
    for (int s = 32; s > 0; s >>= 1) part += __shfl_down(part, s, 64);
    __shared__ int wsum[SCAN_B / 64];
    if ((t & 63) == 0) wsum[t >> 6] = part;
    __syncthreads();
    int base = 0;
#pragma unroll
    for (int k = 0; k < SCAN_B / 64; ++k) base += wsum[k];   // broadcast reads

    // --- local inclusive scan of v ---
    __shared__ int sd[SCAN_B];
    sd[t] = v;
    __syncthreads();
    for (int s = 1; s < SCAN_B; s <<= 1) {
        int u = (t >= s) ? sd[t - s] : 0;
        __syncthreads();
        sd[t] += u;
        __syncthreads();
    }
    int excl = base + sd[t] - v;
    if (i < N_NODES) offsets[i] = excl;
    if (i == N_NODES - 1) offsets[N_NODES] = excl + v;   // == N_EDGES
}

// Atomic-free fill: offsets (200KB) is L2-resident.
__global__ __launch_bounds__(256) void fill_free_kernel(
    const int* __restrict__ dst, const int* __restrict__ rank,
    const int* __restrict__ offsets, int* __restrict__ edge_ids)
{
    int e = blockIdx.x * 256 + threadIdx.x;
    if (e < N_EDGES) edge_ids[offsets[dst[e]] + rank[e]] = e;
}

// ---------------------------------------------------------------------------
// Fused aggregate + GEMM. Per block: 32-node tile.
//   Phase W: batch-load W (16 float4/thread, one L2 round-trip) -> Wl
//            granule-swizzled (conflict-free GEMM reads).
//   Phase G: 8 node-streams x 32 lanes, 4 rounds; windowed-8 gather (8
//            outstanding 512B e_h rows per stream), multiply by h, write
//            tile row to Al (LDS). A never goes to HBM.
//   Phase M: proven 4x4-per-thread GEMM epilogue, bias+norm, store out.
// LDS 80KB -> 2 blocks/CU; 16 outstanding rows/wave covers HBM latency.
// ---------------------------------------------------------------------------
__global__ __launch_bounds__(256, 2) void fused_agg_gemm(
    const float* __restrict__ h, const float* __restrict__ e_h,
    const float* __restrict__ norm, const float* __restrict__ W,
    const float* __restrict__ b, const int* __restrict__ offsets,
    const int* __restrict__ edge_ids, float* __restrict__ out)
{
    __shared__ float Wl[D * D];       // 64KB
    __shared__ float Al[TILE_N * D];  // 16KB
    const int tid = threadIdx.x;
    const int n0  = blockIdx.x * TILE_N;

    // ---- Phase W: batch all 16 loads, then all 16 stores ----
    float4 wreg[16];
#pragma unroll
    for (int it = 0; it < 16; ++it) {
        int group = it * 256 + tid;
        int c  = group >> 5;
        int kg = group & 31;
        wreg[it] = *(const float4*)(W + (size_t)c * D + (kg << 2));
    }
#pragma unroll
    for (int it = 0; it < 16; ++it) {
        int group = it * 256 + tid;
        int c  = group >> 5;
        int kg = group & 31;
        int g  = (kg + c) & 31;
        *(float4*)(Wl + c * D + (g << 2)) = wreg[it];
    }

    // ---- Phase G: gather-aggregate 32 nodes (8 streams x 4 rounds) ----
    const int lane = tid & 31;
    const float* eb = e_h + (lane << 2);
    for (int r = 0; r < 4; ++r) {
        const int nl   = (tid >> 5) + (r << 3);
        const int node = n0 + nl;

        float4 a0 = make_float4(0.f, 0.f, 0.f, 0.f);
        float4 a1 = a0, a2 = a0, a3 = a0;

        if (node < N_NODES) {
            const int beg = offsets[node];
            const int end = offsets[node + 1];
            for (int i = beg; i < end; i += 8) {
                const int m = end - i;          // >= 1
                int i0, i1, i2, i3, i4, i5, i6, i7;
                i0 = edge_ids[i];
                if (m > 1) i1 = edge_ids[i + 1];
                if (m > 2) i2 = edge_ids[i + 2];
                if (m > 3) i3 = edge_ids[i + 3];
                if (m > 4) i4 = edge_ids[i + 4];
                if (m > 5) i5 = edge_ids[i + 5];
                if (m > 6) i6 = edge_ids[i + 6];
                if (m > 7) i7 = edge_ids[i + 7];

                float4 v0, v1, v2, v3, v4, v5, v6, v7;
                v0 = *(const float4*)(eb + ((size_t)i0 << 7));
                if (m > 1) v1 = *(const float4*)(eb + ((size_t)i1 << 7));
                if (m > 2) v2 = *(const float4*)(eb + ((size_t)i2 << 7));
                if (m > 3) v3 = *(const float4*)(eb + ((size_t)i3 << 7));
                if (m > 4) v4 = *(const float4*)(eb + ((size_t)i4 << 7));
                if (m > 5) v5 = *(const float4*)(eb + ((size_t)i5 << 7));
                if (m > 6) v6 = *(const float4*)(eb + ((size_t)i6 << 7));
                if (m > 7) v7 = *(const float4*)(eb + ((size_t)i7 << 7));

                a0.x += v0.x; a0.y += v0.y; a0.z += v0.z; a0.w += v0.w;
                if (m > 1) { a1.x += v1.x; a1.y += v1.y; a1.z += v1.z; a1.w += v1.w; }
                if (m > 2) { a2.x += v2.x; a2.y += v2.y; a2.z += v2.z; a2.w += v2.w; }
                if (m > 3) { a3.x += v3.x; a3.y += v3.y; a3.z += v3.z; a3.w += v3.w; }
                if (m > 4) { a0.x += v4.x; a0.y += v4.y; a0.z += v4.z; a0.w += v4.w; }
                if (m > 5) { a1.x += v5.x; a1.y += v5.y; a1.z += v5.z; a1.w += v5.w; }
                if (m > 6) { a2.x += v6.x; a2.y += v6.y; a2.z += v6.z; a2.w += v6.w; }
                if (m > 7) { a3.x += v7.x; a3.y += v7.y; a3.z += v7.z; a3.w += v7.w; }
            }
            a0.x += a1.x + a2.x + a3.x;
            a0.y += a1.y + a2.y + a3.y;
            a0.z += a1.z + a2.z + a3.z;
            a0.w += a1.w + a2.w + a3.w;

            float4 hv = *(const float4*)(h + ((size_t)node << 7) + (lane << 2));
            a0.x *= hv.x; a0.y *= hv.y; a0.z *= hv.z; a0.w *= hv.w;
        }
        *(float4*)(Al + nl * D + (lane << 2)) = a0;
    }
    __syncthreads();

    // ---- Phase M: GEMM epilogue (proven structure) ----
    const int cg = tid & 31;
    const int ng = tid >> 5;
    float facc[4][4];
#pragma unroll
    for (int i = 0; i < 4; ++i)
#pragma unroll
        for (int j = 0; j < 4; ++j) facc[i][j] = 0.f;

#pragma unroll 4
    for (int kc = 0; kc < 32; ++kc) {
        float4 a[4];
#pragma unroll
        for (int i = 0; i < 4; ++i)
            a[i] = *(const float4*)(Al + (ng * 4 + i) * D + (kc << 2));
        float4 w[4];
#pragma unroll
        for (int j = 0; j < 4; ++j) {
            int c = cg + 32 * j;
            int g = (kc + c) & 31;
            w[j] = *(const float4*)(Wl + c * D + (g << 2));
        }
#pragma unroll
        for (int i = 0; i < 4; ++i)
#pragma unroll
            for (int j = 0; j < 4; ++j)
                facc[i][j] += a[i].x * w[j].x + a[i].y * w[j].y +
                              a[i].z * w[j].z + a[i].w * w[j].w;
    }
    float bias[4];
#pragma unroll
    for (int j = 0; j < 4; ++j) bias[j] = b[cg + 32 * j];
#pragma unroll
    for (int i = 0; i < 4; ++i) {
        int n = n0 + ng * 4 + i;
        if (n >= N_NODES) break;
        float nv = norm[n];
#pragma unroll
        for (int j = 0; j < 4; ++j)
            out[(size_t)n * D + cg + 32 * j] = (facc[i][j] + bias[j]) * nv;
    }
}

// ===========================================================================
// Fallback (tiny ws): float-atomic scatter + fused gemm
// ===========================================================================
__global__ __launch_bounds__(256) void scatter_kernel(
    const float* __restrict__ e_h, const int* __restrict__ dst,
    float* __restrict__ S)
{
    long long idx = (long long)blockIdx.x * 256 + threadIdx.x;
    int edge = (int)(idx >> 5);
    if (edge >= N_EDGES) return;
    int f = ((int)idx & 31) << 2;
    const float4 v = *(const float4*)(e_h + (size_t)edge * D + f);
    float* p = S + (size_t)dst[edge] * D + f;
    atomicAdd(p + 0, v.x);
    atomicAdd(p + 1, v.y);
    atomicAdd(p + 2, v.z);
    atomicAdd(p + 3, v.w);
}

__global__ __launch_bounds__(256, 2) void gemm_kernel(
    const float* __restrict__ h, const float* __restrict__ S,
    const float* __restrict__ norm, const float* __restrict__ W,
    const float* __restrict__ b, float* __restrict__ out)
{
    __shared__ float Wl[D * D];
    __shared__ float Al[TILE_N * D];
    const int tid = threadIdx.x;
    const int n0  = blockIdx.x * TILE_N;

    for (int it = 0; it < 16; ++it) {
        int group = it * 256 + tid;
        int c  = group >> 5;
        int kg = group & 31;
        float4 wv = *(const float4*)(W + (size_t)c * D + (kg << 2));
        int g = (kg + c) & 31;
        *(float4*)(Wl + c * D + (g << 2)) = wv;
    }
    for (int it = 0; it < 4; ++it) {
        int group = it * 256 + tid;
        int nl = group >> 5;
        int f  = (group & 31) << 2;
        int n  = n0 + nl;
        float4 a = make_float4(0.f, 0.f, 0.f, 0.f);
        if (n < N_NODES) {
            float4 hv = *(const float4*)(h + (size_t)n * D + f);
            float4 sv = *(const float4*)(S + (size_t)n * D + f);
            a = make_float4(hv.x * sv.x, hv.y * sv.y, hv.z * sv.z, hv.w * sv.w);
        }
        *(float4*)(Al + nl * D + f) = a;
    }
    __syncthreads();

    const int cg = tid & 31;
    const int ng = tid >> 5;
    float facc[4][4];
#pragma unroll
    for (int i = 0; i < 4; ++i)
#pragma unroll
        for (int j = 0; j < 4; ++j) facc[i][j] = 0.f;

#pragma unroll 4
    for (int kc = 0; kc < 32; ++kc) {
        float4 a[4];
#pragma unroll
        for (int i = 0; i < 4; ++i)
            a[i] = *(const float4*)(Al + (ng * 4 + i) * D + (kc << 2));
        float4 w[4];
#pragma unroll
        for (int j = 0; j < 4; ++j) {
            int c = cg + 32 * j;
            int g = (kc + c) & 31;
            w[j] = *(const float4*)(Wl + c * D + (g << 2));
        }
#pragma unroll
        for (int i = 0; i < 4; ++i)
#pragma unroll
            for (int j = 0; j < 4; ++j)
                facc[i][j] += a[i].x * w[j].x + a[i].y * w[j].y +
                              a[i].z * w[j].z + a[i].w * w[j].w;
    }
    float bias[4];
#pragma unroll
    for (int j = 0; j < 4; ++j) bias[j] = b[cg + 32 * j];
#pragma unroll
    for (int i = 0; i < 4; ++i) {
        int n = n0 + ng * 4 + i;
        if (n >= N_NODES) break;
        float nv = norm[n];
#pragma unroll
        for (int j = 0; j < 4; ++j)
            out[(size_t)n * D + cg + 32 * j] = (facc[i][j] + bias[j]) * nv;
    }
}

// ===========================================================================
extern "C" void kernel_launch(void* const* d_in, const int* in_sizes, int n_in,
                              void* d_out, int out_size, void* d_ws, size_t ws_size,
                              hipStream_t stream) {
    const float* h    = (const float*)d_in[0];
    const float* e_h  = (const float*)d_in[1];
    const float* norm = (const float*)d_in[2];
    const int*   dst  = (const int*)d_in[3];
    const float* W    = (const float*)d_in[4];
    const float* b    = (const float*)d_in[5];
    float* out = (float*)d_out;

    // ws layout: cnt[N] | offsets[N+1] | rank[E] | edge_ids[E]  (~5.2 MB)
    const size_t ints_needed = (size_t)N_NODES + (N_NODES + 1) + 2 * (size_t)N_EDGES;
    const size_t full_bytes  = ints_needed * sizeof(int);

    if (ws_size >= full_bytes) {
        int* cnt      = (int*)d_ws;
        int* offsets  = cnt + N_NODES;
        int* rank     = offsets + N_NODES + 1;
        int* edge_ids = rank + N_EDGES;

        hipMemsetAsync(cnt, 0, (size_t)N_NODES * sizeof(int), stream);

        int eblocks = (N_EDGES + 255) / 256;
        hist_rank_kernel<<<eblocks, 256, 0, stream>>>(dst, cnt, rank);
        scan_offsets_kernel<<<N_SCAN_BLOCKS, SCAN_B, 0, stream>>>(cnt, offsets);
        fill_free_kernel<<<eblocks, 256, 0, stream>>>(dst, rank, offsets, edge_ids);

        int gblocks = (N_NODES + TILE_N - 1) / TILE_N;  // 1563
        fused_agg_gemm<<<gblocks, 256, 0, stream>>>(h, e_h, norm, W, b,
                                                    offsets, edge_ids, out);
    } else {
        const size_t s_bytes = (size_t)N_NODES * D * sizeof(float);
        float* S = (ws_size >= s_bytes) ? (float*)d_ws : out;
        hipMemsetAsync(S, 0, s_bytes, stream);
        int scatter_blocks = (N_EDGES * 32 + 255) / 256;
        scatter_kernel<<<scatter_blocks, 256, 0, stream>>>(e_h, dst, S);
        int gemm_blocks = (N_NODES + TILE_N - 1) / TILE_N;
        gemm_kernel<<<gemm_blocks, 256, 0, stream>>>(h, S, norm, W, b, out);
    }
}